// Round 9
// baseline (297.474 us; speedup 1.0000x reference)
//
#include <hip/hip_runtime.h>

#define LN_EPS 1e-5f

typedef __attribute__((ext_vector_type(8))) short bf16x8;
typedef __attribute__((ext_vector_type(4))) float f32x4;

// Bucketed CSR build parameters: bucket = 128 consecutive dst nodes.
#define BSH 7
#define BSPAN 128
#define BCAP 4096      // staging capacity per bucket (mean 2046, std ~45)
#define BIN_TILE 4096  // edges per bin block (16 per thread)

__device__ __forceinline__ unsigned short f2bf(float f) {
    union { float f; unsigned u; } x; x.f = f;
    unsigned r = (x.u + 0x7FFFu + ((x.u >> 16) & 1u)) >> 16;
    return (unsigned short)r;
}
__device__ __forceinline__ float bfbits2f(unsigned hi) {  // hi = bf16 bits already in [31:16]
    union { unsigned u; float f; } x; x.u = hi; return x.f;
}
// 2x f32 -> packed bf16 (RNE), gfx950 single instruction
__device__ __forceinline__ unsigned cvtpk_bf16(float lo, float hi) {
    unsigned r;
    asm("v_cvt_pk_bf16_f32 %0, %1, %2" : "=v"(r) : "v"(lo), "v"(hi));
    return r;
}

// ---------- W packing (+ gcur zeroing) ----------
// Wp[(((kc*128 + col)*4 + kb)*8) + j] = W[(kc*32 + kb*8 + j)*128 + col]
__global__ void packw_k(const float* __restrict__ W1, const float* __restrict__ W2,
                        unsigned short* __restrict__ Wp1, unsigned short* __restrict__ Wp2,
                        int* __restrict__ gcur, int nb) {
    int idx = blockIdx.x * blockDim.x + threadIdx.x;  // 0..32767
    if (blockIdx.x == 0) {
        for (int i = threadIdx.x; i < nb; i += 256) gcur[i] = 0;
    }
    const float* W = (idx < 16384) ? W1 : W2;
    unsigned short* Wp = (idx < 16384) ? Wp1 : Wp2;
    int t = idx & 16383;
    int k = t >> 7, col = t & 127;
    int kc = k >> 5, kr = k & 31, kb = kr >> 3, j = kr & 7;
    Wp[(((kc * 128 + col) * 4 + kb) * 8) + j] = f2bf(W[k * 128 + col]);
}

// ---------- bucketed CSR build ----------
__global__ __launch_bounds__(256) void bin_k(const int* __restrict__ src,
                                             const int* __restrict__ dst,
                                             int* __restrict__ gcur,
                                             unsigned* __restrict__ staging,
                                             int nE, int nb) {
    __shared__ int cnt[512];
    __shared__ int gbase[512];
    int tid = threadIdx.x;
    for (int i = tid; i < nb; i += 256) cnt[i] = 0;
    __syncthreads();
    int e0 = blockIdx.x * BIN_TILE;
    unsigned pk[16];
    int bk[16];
    int rk[16];
#pragma unroll
    for (int i = 0; i < 16; ++i) {
        int e = e0 + i * 256 + tid;
        if (e < nE) {
            int s = src[e];
            int d = dst[e];
            int b = d >> BSH;
            rk[i] = atomicAdd(&cnt[b], 1);
            bk[i] = b;
            pk[i] = (unsigned)s | ((unsigned)(d & (BSPAN - 1)) << 17);
        } else {
            bk[i] = -1;
        }
    }
    __syncthreads();
    for (int i = tid; i < nb; i += 256) gbase[i] = atomicAdd(&gcur[i], cnt[i]);
    __syncthreads();
#pragma unroll
    for (int i = 0; i < 16; ++i) {
        if (bk[i] >= 0)
            staging[(size_t)bk[i] * BCAP + gbase[bk[i]] + rk[i]] = pk[i];
    }
}

// Pass 2: one block per bucket. Inline prefix over gcur, then per-node counts +
// 128-wide scan + scatter, all in LDS. Produces rowptr, dinv, dst-grouped eidx.
__global__ __launch_bounds__(256) void build_k(const unsigned* __restrict__ staging,
                                               const int* __restrict__ gcur,
                                               int* __restrict__ rowptr,
                                               int* __restrict__ eidx,
                                               float* __restrict__ dinv, int n, int nE) {
    __shared__ int cnt[BSPAN];
    __shared__ int off[BSPAN];
    __shared__ int s[BSPAN];
    __shared__ int red[4];
    int b = blockIdx.x;
    int tid = threadIdx.x;
    if (tid < BSPAN) cnt[tid] = 0;
    int part = 0;
    for (int i = tid; i < b; i += 256) part += gcur[i];
#pragma unroll
    for (int o = 32; o > 0; o >>= 1) part += __shfl_down(part, o);
    if ((tid & 63) == 0) red[tid >> 6] = part;
    __syncthreads();
    int base = red[0] + red[1] + red[2] + red[3];
    int total = gcur[b];
    if (b == 0 && tid == 0) rowptr[n] = nE;

    const unsigned* stg = staging + (size_t)b * BCAP;
    unsigned ent[16];
#pragma unroll
    for (int k = 0; k < 16; ++k) {
        int i = tid + k * 256;
        unsigned e = 0xFFFFFFFFu;
        if (i < total) {
            e = stg[i];
            atomicAdd(&cnt[(e >> 17) & (BSPAN - 1)], 1);
        }
        ent[k] = e;
    }
    __syncthreads();
    if (tid < BSPAN) s[tid] = cnt[tid];
    __syncthreads();
    for (int o = 1; o < BSPAN; o <<= 1) {
        int t = (tid < BSPAN && tid >= o) ? s[tid - o] : 0;
        __syncthreads();
        if (tid < BSPAN) s[tid] += t;
        __syncthreads();
    }
    if (tid < BSPAN) {
        int excl = s[tid] - cnt[tid];
        off[tid] = excl;
        int node = b * BSPAN + tid;
        if (node < n) {
            rowptr[node] = base + excl;
            dinv[node] = rsqrtf((float)(cnt[tid] + 1));
        }
    }
    __syncthreads();
#pragma unroll
    for (int k = 0; k < 16; ++k) {
        unsigned e = ent[k];
        if (e != 0xFFFFFFFFu) {
            int ld = (e >> 17) & (BSPAN - 1);
            int p = atomicAdd(&off[ld], 1);
            eidx[base + p] = (int)(e & 0x1FFFFu);
        }
    }
}

// ---------- MFMA GEMM: Yseg = bf16( dinv[r] * (A[r,:] @ W) ), column-blocked out ----------
// Y layout: [4][npad][32] bf16 (segment s holds dims [32s,32s+32)).
// A_F32: A is fp32 row-major (layer-1 input x); else A is column-blocked bf16 [4][npad][32].
template <bool A_F32>
__global__ __launch_bounds__(256) void mfma_gemm_k(const void* __restrict__ Ain,
                                                   const unsigned short* __restrict__ Wp,
                                                   const float* __restrict__ dinv,
                                                   unsigned short* __restrict__ Y,
                                                   int n, int npad) {
    int wid = threadIdx.x >> 6;
    int lane = threadIdx.x & 63;
    int rgrp = wid & 1;
    int cgrp = wid >> 1;
    int row0 = blockIdx.x * 64 + rgrp * 32;
    int m = lane & 15;
    int kb = lane >> 4;  // 0..3

    f32x4 acc[2][4] = {};
#pragma unroll
    for (int kc = 0; kc < 4; ++kc) {
        bf16x8 a[2], b[4];
#pragma unroll
        for (int rs = 0; rs < 2; ++rs) {
            int r = row0 + rs * 16 + m;
            if (A_F32) {
                f32x4 f0 = {0.f, 0.f, 0.f, 0.f}, f1 = {0.f, 0.f, 0.f, 0.f};
                if (r < n) {
                    const float* ap = (const float*)Ain + (size_t)r * 128 + kc * 32 + kb * 8;
                    f0 = *(const f32x4*)ap;
                    f1 = *(const f32x4*)(ap + 4);
                }
                unsigned* w = (unsigned*)&a[rs];
                w[0] = cvtpk_bf16(f0.x, f0.y);
                w[1] = cvtpk_bf16(f0.z, f0.w);
                w[2] = cvtpk_bf16(f1.x, f1.y);
                w[3] = cvtpk_bf16(f1.z, f1.w);
            } else {
                // column-blocked: segment kc, node r, dims [kb*8, kb*8+8)
                a[rs] = *(const bf16x8*)((const unsigned short*)Ain +
                                         ((size_t)kc * npad + r) * 32 + kb * 8);
            }
        }
#pragma unroll
        for (int cf = 0; cf < 4; ++cf) {
            int col = cgrp * 64 + cf * 16 + m;
            b[cf] = *(const bf16x8*)(Wp + (((kc * 128 + col) * 4 + kb) * 8));
        }
#pragma unroll
        for (int rs = 0; rs < 2; ++rs)
#pragma unroll
            for (int cf = 0; cf < 4; ++cf)
                acc[rs][cf] = __builtin_amdgcn_mfma_f32_16x16x32_bf16(a[rs], b[cf], acc[rs][cf], 0, 0, 0);
    }
    // D layout: row = (lane>>4)*4 + reg, col = lane&15
#pragma unroll
    for (int rs = 0; rs < 2; ++rs) {
        int rbase = row0 + rs * 16 + kb * 4;
#pragma unroll
        for (int r = 0; r < 4; ++r) {
            int row = rbase + r;
            if (row >= n) continue;
            float dv = dinv[row];
#pragma unroll
            for (int cf = 0; cf < 4; ++cf) {
                int col = cgrp * 64 + cf * 16 + m;
                Y[((size_t)(col >> 5) * npad + row) * 32 + (col & 31)] = f2bf(acc[rs][cf][r] * dv);
            }
        }
    }
}

// ---------- fused gather-aggregate + bias + LN + ReLU (segmented gather) ----------
// H layout: [4][npad][32] bf16. One wave per node. The wave walks its edge list 4
// times, once per 32-dim segment: per-segment gather working set = 3.2 MB (fits the
// 4 MB/XCD L2). Lane roles per segment: eslot = lane>>2 (16 edges/instruction),
// l = lane&3 (uint4 = 8 dims). After the xor-combine over eslots, lane-group
// (lane>>2)&3 == k retains segment k -> every 16-lane group holds the full row;
// LN runs fused exactly as before.
#define ACCS(u, s) { \
    a0 = fmaf(bfbits2f((u).x << 16), s, a0); a1 = fmaf(bfbits2f((u).x & 0xFFFF0000u), s, a1); \
    a2 = fmaf(bfbits2f((u).y << 16), s, a2); a3 = fmaf(bfbits2f((u).y & 0xFFFF0000u), s, a3); \
    a4 = fmaf(bfbits2f((u).z << 16), s, a4); a5 = fmaf(bfbits2f((u).z & 0xFFFF0000u), s, a5); \
    a6 = fmaf(bfbits2f((u).w << 16), s, a6); a7 = fmaf(bfbits2f((u).w & 0xFFFF0000u), s, a7); }

// Gather 16 edges (one uint4 load instruction): edge eb+eslot, lane's 8 dims.
#define GS16(EB, U, S) { \
    int ee = (EB) + eslot; \
    bool pp = ee < end; \
    int ec = pp ? ee : (end - 1); \
    int ix = eidx[ec]; \
    size_t ii = (size_t)(pp ? ix : node); \
    U = Hseg[segbase + ii * 4 + l]; \
    S = pp ? 1.0f : 0.0f; }

template <bool OUT_BF16>
__global__ __launch_bounds__(256) void agg_ln_k(const unsigned short* __restrict__ Hs,
                                                const float* __restrict__ dinv,
                                                const int* __restrict__ rowptr,
                                                const int* __restrict__ eidx,
                                                const float* __restrict__ bias,
                                                const float* __restrict__ g,
                                                const float* __restrict__ beta,
                                                void* __restrict__ out, int n, int npad) {
    int wave = (blockIdx.x * blockDim.x + threadIdx.x) >> 6;
    int lane = threadIdx.x & 63;
    int node = (wave < n) ? wave : (n - 1);  // clamp (keeps barriers uniform)
    int eslot = lane >> 2;   // 0..15
    int l = lane & 3;        // 0..3
    const uint4* Hseg = (const uint4*)Hs;  // node segment = 4 x uint4

    int beg = rowptr[node];
    int end = rowptr[node + 1];
    float dt = dinv[node];

    float r0 = 0.f, r1 = 0.f, r2 = 0.f, r3 = 0.f, r4 = 0.f, r5 = 0.f, r6 = 0.f, r7 = 0.f;
    int myseg = (lane >> 2) & 3;  // which segment this lane retains
#pragma unroll
    for (int k = 0; k < 4; ++k) {
        size_t segbase = (size_t)k * npad * 4;  // in uint4 units
        float a0 = 0.f, a1 = 0.f, a2 = 0.f, a3 = 0.f, a4 = 0.f, a5 = 0.f, a6 = 0.f, a7 = 0.f;
        {   // self segment: all lanes load (4 distinct addrs, broadcast); only eslot 0 counts
            uint4 sv = Hseg[segbase + (size_t)node * 4 + l];
            float ss = (eslot == 0) ? 1.0f : 0.0f;
            ACCS(sv, ss);
        }
        if (beg < end) {
            uint4 c0, c1;
            float s0, s1;
            GS16(beg, c0, s0);
            GS16(beg + 16, c1, s1);
            for (int eb = beg + 32;; eb += 32) {
                bool more = eb < end;  // wave-uniform
                uint4 n0 = c0, n1 = c0;
                float t0 = 0.f, t1 = 0.f;
                if (more) {
                    GS16(eb, n0, t0);
                    GS16(eb + 16, n1, t1);
                }
                ACCS(c0, s0);
                ACCS(c1, s1);
                if (!more) break;
                c0 = n0; c1 = n1;
                s0 = t0; s1 = t1;
            }
        }
        // combine over the 16 edge-slots (lanes with equal l, stride 4)
        a0 += __shfl_xor(a0, 4);  a1 += __shfl_xor(a1, 4);
        a2 += __shfl_xor(a2, 4);  a3 += __shfl_xor(a3, 4);
        a4 += __shfl_xor(a4, 4);  a5 += __shfl_xor(a5, 4);
        a6 += __shfl_xor(a6, 4);  a7 += __shfl_xor(a7, 4);
        a0 += __shfl_xor(a0, 8);  a1 += __shfl_xor(a1, 8);
        a2 += __shfl_xor(a2, 8);  a3 += __shfl_xor(a3, 8);
        a4 += __shfl_xor(a4, 8);  a5 += __shfl_xor(a5, 8);
        a6 += __shfl_xor(a6, 8);  a7 += __shfl_xor(a7, 8);
        a0 += __shfl_xor(a0, 16); a1 += __shfl_xor(a1, 16);
        a2 += __shfl_xor(a2, 16); a3 += __shfl_xor(a3, 16);
        a4 += __shfl_xor(a4, 16); a5 += __shfl_xor(a5, 16);
        a6 += __shfl_xor(a6, 16); a7 += __shfl_xor(a7, 16);
        a0 += __shfl_xor(a0, 32); a1 += __shfl_xor(a1, 32);
        a2 += __shfl_xor(a2, 32); a3 += __shfl_xor(a3, 32);
        a4 += __shfl_xor(a4, 32); a5 += __shfl_xor(a5, 32);
        a6 += __shfl_xor(a6, 32); a7 += __shfl_xor(a7, 32);
        if (myseg == k) {
            r0 = a0; r1 = a1; r2 = a2; r3 = a3;
            r4 = a4; r5 = a5; r6 = a6; r7 = a7;
        }
        if (k < 3) __syncthreads();  // keep the block's 4 waves phase-aligned
    }

    // Lane (within its 16-lane group) holds dims [myseg*32 + l*8, +8).
    int db4 = myseg * 8 + l * 2;  // float4 index of this lane's first 4 dims
    float4 bi0 = ((const float4*)bias)[db4];
    float4 bi1 = ((const float4*)bias)[db4 + 1];
    float v0 = r0 * dt + bi0.x, v1 = r1 * dt + bi0.y;
    float v2 = r2 * dt + bi0.z, v3 = r3 * dt + bi0.w;
    float v4 = r4 * dt + bi1.x, v5 = r5 * dt + bi1.y;
    float v6 = r6 * dt + bi1.z, v7 = r7 * dt + bi1.w;

    float sum = ((v0 + v1) + (v2 + v3)) + ((v4 + v5) + (v6 + v7));
    sum += __shfl_xor(sum, 1);
    sum += __shfl_xor(sum, 2);
    sum += __shfl_xor(sum, 4);
    sum += __shfl_xor(sum, 8);
    float mu = sum * (1.0f / 128.0f);
    float d0 = v0 - mu, d1 = v1 - mu, d2 = v2 - mu, d3 = v3 - mu;
    float d4 = v4 - mu, d5 = v5 - mu, d6 = v6 - mu, d7 = v7 - mu;
    float vs = ((d0 * d0 + d1 * d1) + (d2 * d2 + d3 * d3)) +
               ((d4 * d4 + d5 * d5) + (d6 * d6 + d7 * d7));
    vs += __shfl_xor(vs, 1);
    vs += __shfl_xor(vs, 2);
    vs += __shfl_xor(vs, 4);
    vs += __shfl_xor(vs, 8);
    float rstd = rsqrtf(vs * (1.0f / 128.0f) + LN_EPS);

    float4 gg0 = ((const float4*)g)[db4];
    float4 gg1 = ((const float4*)g)[db4 + 1];
    float4 bb0 = ((const float4*)beta)[db4];
    float4 bb1 = ((const float4*)beta)[db4 + 1];
    float o0 = fmaxf(d0 * rstd * gg0.x + bb0.x, 0.0f);
    float o1 = fmaxf(d1 * rstd * gg0.y + bb0.y, 0.0f);
    float o2 = fmaxf(d2 * rstd * gg0.z + bb0.z, 0.0f);
    float o3 = fmaxf(d3 * rstd * gg0.w + bb0.w, 0.0f);
    float o4 = fmaxf(d4 * rstd * gg1.x + bb1.x, 0.0f);
    float o5 = fmaxf(d5 * rstd * gg1.y + bb1.y, 0.0f);
    float o6 = fmaxf(d6 * rstd * gg1.z + bb1.z, 0.0f);
    float o7 = fmaxf(d7 * rstd * gg1.w + bb1.w, 0.0f);

    if (wave < n && lane < 16) {  // one 16-lane group covers the full row
        if (OUT_BF16) {
            // column-blocked bf16: segment myseg, node wave, dims [l*8, l*8+8)
            uint4 pk;
            pk.x = (unsigned)f2bf(o0) | ((unsigned)f2bf(o1) << 16);
            pk.y = (unsigned)f2bf(o2) | ((unsigned)f2bf(o3) << 16);
            pk.z = (unsigned)f2bf(o4) | ((unsigned)f2bf(o5) << 16);
            pk.w = (unsigned)f2bf(o6) | ((unsigned)f2bf(o7) << 16);
            ((uint4*)out)[((size_t)myseg * npad + wave) * 4 + l] = pk;
        } else {
            float4* o = (float4*)out;
            o[(size_t)wave * 32 + db4]     = make_float4(o0, o1, o2, o3);
            o[(size_t)wave * 32 + db4 + 1] = make_float4(o4, o5, o6, o7);
        }
    }
}

extern "C" void kernel_launch(void* const* d_in, const int* in_sizes, int n_in,
                              void* d_out, int out_size, void* d_ws, size_t ws_size,
                              hipStream_t stream) {
    const float* x   = (const float*)d_in[0];
    const int*   ei  = (const int*)d_in[1];
    const float* W1  = (const float*)d_in[2];
    const float* b1  = (const float*)d_in[3];
    const float* g1  = (const float*)d_in[4];
    const float* be1 = (const float*)d_in[5];
    const float* W2  = (const float*)d_in[6];
    const float* b2  = (const float*)d_in[7];
    const float* g2  = (const float*)d_in[8];
    const float* be2 = (const float*)d_in[9];
    float* out = (float*)d_out;

    int n  = in_sizes[0] / 128;   // 50000
    int nE = in_sizes[1] / 2;     // 800000
    const int* src = ei;
    const int* dst = ei + nE;

    int nb = (n + BSPAN - 1) >> BSH;  // 391 buckets
    int nblk64 = (n + 63) / 64;       // GEMM blocks
    int npad   = nblk64 * 64;         // padded rows for OOB-safe frag loads

    char* p = (char*)d_ws;
    auto carve = [&](size_t bytes) {
        char* r = p;
        p += (bytes + 255) & ~(size_t)255;
        return r;
    };
    float*    dinv    = (float*)carve((size_t)n * 4);
    int*      rowptr  = (int*)carve((size_t)(n + 1) * 4);
    int*      eidx    = (int*)carve((size_t)nE * 4);
    int*      gcur    = (int*)carve((size_t)nb * 4);
    unsigned* staging = (unsigned*)carve((size_t)nb * BCAP * 4);
    unsigned short* Wp1 = (unsigned short*)carve(16384 * 2);
    unsigned short* Wp2 = (unsigned short*)carve(16384 * 2);
    unsigned short* Hs  = (unsigned short*)carve((size_t)npad * 128 * 2);  // col-blocked GEMM out
    unsigned short* Hb  = (unsigned short*)carve((size_t)npad * 128 * 2);  // col-blocked layer-1 result

    dim3 blk(256);
    int nbin = (nE + BIN_TILE - 1) / BIN_TILE;
    int nwave_blocks = (n + 3) / 4;

    // prep: W packing + gcur zero
    packw_k<<<32768 / 256, blk, 0, stream>>>(W1, W2, Wp1, Wp2, gcur, nb);

    // bucketed CSR build
    bin_k<<<nbin, blk, 0, stream>>>(src, dst, gcur, staging, nE, nb);
    build_k<<<nb, blk, 0, stream>>>(staging, gcur, rowptr, eidx, dinv, n, nE);

    // layer 1 (fp32 x converted in-register inside GEMM) -> Hs (column-blocked)
    mfma_gemm_k<true><<<nblk64, blk, 0, stream>>>(x, Wp1, dinv, Hs, n, npad);
    agg_ln_k<true><<<nwave_blocks, blk, 0, stream>>>(Hs, dinv, rowptr, eidx, b1, g1, be1, Hb, n, npad);

    // layer 2 (Hb padding rows are garbage; OOB accum rows are discarded by store guard)
    mfma_gemm_k<false><<<nblk64, blk, 0, stream>>>(Hb, Wp2, dinv, Hs, n, npad);
    agg_ln_k<false><<<nwave_blocks, blk, 0, stream>>>(Hs, dinv, rowptr, eidx, b2, g2, be2, out, n, npad);
}

// Round 10
// 209.574 us; speedup vs baseline: 1.4194x; 1.4194x over previous
//
#include <hip/hip_runtime.h>

#define LN_EPS 1e-5f

typedef __attribute__((ext_vector_type(8))) short bf16x8;
typedef __attribute__((ext_vector_type(4))) float f32x4;

// Bucketed CSR build parameters: bucket = 128 consecutive dst nodes.
#define BSH 7
#define BSPAN 128
#define BCAP 4096   // staging capacity per bucket (mean 2048, std ~45)
#define BIN_TILE 4096  // edges per bin_k block (16 per thread)

__device__ __forceinline__ unsigned short f2bf(float f) {
    union { float f; unsigned u; } x; x.f = f;
    unsigned r = (x.u + 0x7FFFu + ((x.u >> 16) & 1u)) >> 16;
    return (unsigned short)r;
}
__device__ __forceinline__ float bfbits2f(unsigned hi) {  // hi = bf16 bits already in [31:16]
    union { unsigned u; float f; } x; x.u = hi; return x.f;
}
// 2x f32 -> packed bf16 (RNE), gfx950 single instruction
__device__ __forceinline__ unsigned cvtpk_bf16(float lo, float hi) {
    unsigned r;
    asm("v_cvt_pk_bf16_f32 %0, %1, %2" : "=v"(r) : "v"(lo), "v"(hi));
    return r;
}

// ---------- W packing (+ gcur zeroing) ----------
// Wp[(((kc*128 + col)*4 + kb)*8) + j] = W[(kc*32 + kb*8 + j)*128 + col]
__global__ void packw_k(const float* __restrict__ W1, const float* __restrict__ W2,
                        unsigned short* __restrict__ Wp1, unsigned short* __restrict__ Wp2,
                        int* __restrict__ gcur, int nb) {
    int idx = blockIdx.x * blockDim.x + threadIdx.x;  // 0..32767
    if (blockIdx.x == 0) {
        for (int i = threadIdx.x; i < nb; i += 256) gcur[i] = 0;
    }
    const float* W = (idx < 16384) ? W1 : W2;
    unsigned short* Wp = (idx < 16384) ? Wp1 : Wp2;
    int t = idx & 16383;
    int k = t >> 7, col = t & 127;
    int kc = k >> 5, kr = k & 31, kb = kr >> 3, j = kr & 7;
    Wp[(((kc * 128 + col) * 4 + kb) * 8) + j] = f2bf(W[k * 128 + col]);
}

// ---------- bucketed CSR build ----------
// Pass 1: counting-bin BIN_TILE edges into nb buckets via LDS counters; reserve a
// contiguous run per (block,bucket) with one global atomic per bucket; write packed
// entries (src | localdst<<17) into bucket-major staging.
__global__ __launch_bounds__(256) void bin_k(const int* __restrict__ src,
                                             const int* __restrict__ dst,
                                             int* __restrict__ gcur,
                                             unsigned* __restrict__ staging,
                                             int nE, int nb) {
    __shared__ int cnt[512];
    __shared__ int gbase[512];
    int tid = threadIdx.x;
    for (int i = tid; i < nb; i += 256) cnt[i] = 0;
    __syncthreads();
    int e0 = blockIdx.x * BIN_TILE;
    unsigned pk[16];
    int bk[16];
    int rk[16];
#pragma unroll
    for (int i = 0; i < 16; ++i) {
        int e = e0 + i * 256 + tid;
        if (e < nE) {
            int s = src[e];
            int d = dst[e];
            int b = d >> BSH;
            rk[i] = atomicAdd(&cnt[b], 1);
            bk[i] = b;
            pk[i] = (unsigned)s | ((unsigned)(d & (BSPAN - 1)) << 17);
        } else {
            bk[i] = -1;
        }
    }
    __syncthreads();
    for (int i = tid; i < nb; i += 256) gbase[i] = atomicAdd(&gcur[i], cnt[i]);
    __syncthreads();
#pragma unroll
    for (int i = 0; i < 16; ++i) {
        if (bk[i] >= 0)
            staging[(size_t)bk[i] * BCAP + gbase[bk[i]] + rk[i]] = pk[i];
    }
}

// Pass 2: one block per bucket. Inline prefix over gcur (replaces bscan launch),
// then per-node counts + 128-wide scan + scatter, all in LDS.
// Produces rowptr, dinv, and the final dst-grouped eidx.
__global__ __launch_bounds__(256) void build_k(const unsigned* __restrict__ staging,
                                               const int* __restrict__ gcur,
                                               int* __restrict__ rowptr,
                                               int* __restrict__ eidx,
                                               float* __restrict__ dinv, int n, int nE) {
    __shared__ int cnt[BSPAN];
    __shared__ int off[BSPAN];
    __shared__ int s[BSPAN];
    __shared__ int red[4];
    int b = blockIdx.x;
    int tid = threadIdx.x;
    if (tid < BSPAN) cnt[tid] = 0;
    // base = sum gcur[0..b) via block reduction
    int part = 0;
    for (int i = tid; i < b; i += 256) part += gcur[i];
#pragma unroll
    for (int o = 32; o > 0; o >>= 1) part += __shfl_down(part, o);
    if ((tid & 63) == 0) red[tid >> 6] = part;
    __syncthreads();
    int base = red[0] + red[1] + red[2] + red[3];
    int total = gcur[b];
    if (b == 0 && tid == 0) rowptr[n] = nE;

    const unsigned* stg = staging + (size_t)b * BCAP;
    unsigned ent[16];  // BCAP/256 = 16 max entries per thread; statically indexed
#pragma unroll
    for (int k = 0; k < 16; ++k) {
        int i = tid + k * 256;
        unsigned e = 0xFFFFFFFFu;  // sentinel: valid entries have bits[31:24]==0
        if (i < total) {
            e = stg[i];
            atomicAdd(&cnt[(e >> 17) & (BSPAN - 1)], 1);
        }
        ent[k] = e;
    }
    __syncthreads();
    // exclusive scan of cnt[0..127]
    if (tid < BSPAN) s[tid] = cnt[tid];
    __syncthreads();
    for (int o = 1; o < BSPAN; o <<= 1) {
        int t = (tid < BSPAN && tid >= o) ? s[tid - o] : 0;
        __syncthreads();
        if (tid < BSPAN) s[tid] += t;
        __syncthreads();
    }
    if (tid < BSPAN) {
        int excl = s[tid] - cnt[tid];
        off[tid] = excl;  // becomes the scatter cursor
        int node = b * BSPAN + tid;
        if (node < n) {
            rowptr[node] = base + excl;
            dinv[node] = rsqrtf((float)(cnt[tid] + 1));
        }
    }
    __syncthreads();
#pragma unroll
    for (int k = 0; k < 16; ++k) {
        unsigned e = ent[k];
        if (e != 0xFFFFFFFFu) {
            int ld = (e >> 17) & (BSPAN - 1);
            int p = atomicAdd(&off[ld], 1);
            eidx[base + p] = (int)(e & 0x1FFFFu);
        }
    }
}

// ---------- MFMA GEMM: Y[r,:] = bf16( dinv[r] * (A[r,:] @ W) ) ----------
// Block: 256 thr = 4 waves; block tile 64 rows x 128 cols.
// Wave (rgrp = wid&1, cgrp = wid>>1): 32 rows x 64 cols = 2 A-frags x 4 B-frags.
// A_F32: A is fp32 (layer-1 input x), converted in-register via v_cvt_pk_bf16_f32.
template <bool A_F32>
__global__ __launch_bounds__(256) void mfma_gemm_k(const void* __restrict__ Ain,
                                                   const unsigned short* __restrict__ Wp,
                                                   const float* __restrict__ dinv,
                                                   unsigned short* __restrict__ Y, int n) {
    int wid = threadIdx.x >> 6;
    int lane = threadIdx.x & 63;
    int rgrp = wid & 1;
    int cgrp = wid >> 1;
    int row0 = blockIdx.x * 64 + rgrp * 32;
    int m = lane & 15;
    int kb = lane >> 4;  // 0..3

    f32x4 acc[2][4] = {};
#pragma unroll
    for (int kc = 0; kc < 4; ++kc) {
        bf16x8 a[2], b[4];
#pragma unroll
        for (int rs = 0; rs < 2; ++rs) {
            int r = row0 + rs * 16 + m;
            if (A_F32) {
                f32x4 f0 = {0.f, 0.f, 0.f, 0.f}, f1 = {0.f, 0.f, 0.f, 0.f};
                if (r < n) {
                    const float* ap = (const float*)Ain + (size_t)r * 128 + kc * 32 + kb * 8;
                    f0 = *(const f32x4*)ap;
                    f1 = *(const f32x4*)(ap + 4);
                }
                unsigned* w = (unsigned*)&a[rs];
                w[0] = cvtpk_bf16(f0.x, f0.y);
                w[1] = cvtpk_bf16(f0.z, f0.w);
                w[2] = cvtpk_bf16(f1.x, f1.y);
                w[3] = cvtpk_bf16(f1.z, f1.w);
            } else {
                a[rs] = *(const bf16x8*)((const unsigned short*)Ain + (size_t)r * 128 + kc * 32 + kb * 8);
            }
        }
#pragma unroll
        for (int cf = 0; cf < 4; ++cf) {
            int col = cgrp * 64 + cf * 16 + m;
            b[cf] = *(const bf16x8*)(Wp + (((kc * 128 + col) * 4 + kb) * 8));
        }
#pragma unroll
        for (int rs = 0; rs < 2; ++rs)
#pragma unroll
            for (int cf = 0; cf < 4; ++cf)
                acc[rs][cf] = __builtin_amdgcn_mfma_f32_16x16x32_bf16(a[rs], b[cf], acc[rs][cf], 0, 0, 0);
    }
    // D layout: row = (lane>>4)*4 + reg, col = lane&15
#pragma unroll
    for (int rs = 0; rs < 2; ++rs) {
        int rbase = row0 + rs * 16 + kb * 4;
#pragma unroll
        for (int r = 0; r < 4; ++r) {
            int row = rbase + r;
            if (row >= n) continue;
            float dv = dinv[row];
#pragma unroll
            for (int cf = 0; cf < 4; ++cf) {
                int col = cgrp * 64 + cf * 16 + m;
                Y[(size_t)row * 128 + col] = f2bf(acc[rs][cf][r] * dv);
            }
        }
    }
}

// ---------- fused gather-aggregate + bias + LN + ReLU ----------
// One wave per node. Quarter-wave (16 lanes) per edge-row (uint4 = 8 dims/lane).
// 16 edges per iteration (4 gather instructions), software-pipelined depth-2 ->
// 8 outstanding uint4 gathers per wave. Fully branchless: lanes past the degree
// gather the L1-hot self row and are nulled via a x0 scale in the FMA accumulate.
#define ACCS(u, s) { \
    a0 = fmaf(bfbits2f((u).x << 16), s, a0); a1 = fmaf(bfbits2f((u).x & 0xFFFF0000u), s, a1); \
    a2 = fmaf(bfbits2f((u).y << 16), s, a2); a3 = fmaf(bfbits2f((u).y & 0xFFFF0000u), s, a3); \
    a4 = fmaf(bfbits2f((u).z << 16), s, a4); a5 = fmaf(bfbits2f((u).z & 0xFFFF0000u), s, a5); \
    a6 = fmaf(bfbits2f((u).w << 16), s, a6); a7 = fmaf(bfbits2f((u).w & 0xFFFF0000u), s, a7); }

// Load edge-slot (EB+OFF+grp): predicated index select (self row when past end),
// unconditional gather, scale 1/0.
#define GSLOT(EB, OFF, U, S) { \
    int ee = (EB) + (OFF) + grp; \
    bool pp = ee < end; \
    int ec = pp ? ee : (end - 1); \
    int ix = eidx[ec]; \
    int ii = pp ? ix : wave; \
    U = H16[(size_t)ii * 16 + q]; \
    S = pp ? 1.0f : 0.0f; }

template <bool OUT_BF16>
__global__ __launch_bounds__(256) void agg_ln_k(const unsigned short* __restrict__ Hs,
                                                const float* __restrict__ dinv,
                                                const int* __restrict__ rowptr,
                                                const int* __restrict__ eidx,
                                                const float* __restrict__ bias,
                                                const float* __restrict__ g,
                                                const float* __restrict__ beta,
                                                void* __restrict__ out, int n) {
    int wave = (blockIdx.x * blockDim.x + threadIdx.x) >> 6;
    int lane = threadIdx.x & 63;
    if (wave >= n) return;
    int q = lane & 15;
    int grp = lane >> 4;  // 0..3
    const uint4* H16 = (const uint4*)Hs;  // one uint4 = 8 bf16; row = 16 uint4

    int beg = rowptr[wave];
    int end = rowptr[wave + 1];
    float dt = dinv[wave];

    float a0 = 0.f, a1 = 0.f, a2 = 0.f, a3 = 0.f, a4 = 0.f, a5 = 0.f, a6 = 0.f, a7 = 0.f;
    {   // self row (all 4 groups load it -> warms L1 fallback line; scale so only one counts)
        uint4 sv = H16[(size_t)wave * 16 + q];
        float ss = (grp == 0) ? 1.0f : 0.0f;
        ACCS(sv, ss);
    }
    if (beg < end) {
        uint4 c0, c1, c2, c3;
        float s0, s1, s2, s3;
        GSLOT(beg, 0, c0, s0);
        GSLOT(beg, 4, c1, s1);
        GSLOT(beg, 8, c2, s2);
        GSLOT(beg, 12, c3, s3);
        for (int eb = beg + 16;; eb += 16) {
            bool more = eb < end;  // wave-uniform
            uint4 n0 = c0, n1 = c0, n2 = c0, n3 = c0;
            float t0 = 0.f, t1 = 0.f, t2 = 0.f, t3 = 0.f;
            if (more) {
                GSLOT(eb, 0, n0, t0);
                GSLOT(eb, 4, n1, t1);
                GSLOT(eb, 8, n2, t2);
                GSLOT(eb, 12, n3, t3);
            }
            ACCS(c0, s0);
            ACCS(c1, s1);
            ACCS(c2, s2);
            ACCS(c3, s3);
            if (!more) break;
            c0 = n0; c1 = n1; c2 = n2; c3 = n3;
            s0 = t0; s1 = t1; s2 = t2; s3 = t3;
        }
    }
    // combine the 4 quarter-groups (each held a disjoint edge subset)
    a0 += __shfl_xor(a0, 16); a1 += __shfl_xor(a1, 16);
    a2 += __shfl_xor(a2, 16); a3 += __shfl_xor(a3, 16);
    a4 += __shfl_xor(a4, 16); a5 += __shfl_xor(a5, 16);
    a6 += __shfl_xor(a6, 16); a7 += __shfl_xor(a7, 16);
    a0 += __shfl_xor(a0, 32); a1 += __shfl_xor(a1, 32);
    a2 += __shfl_xor(a2, 32); a3 += __shfl_xor(a3, 32);
    a4 += __shfl_xor(a4, 32); a5 += __shfl_xor(a5, 32);
    a6 += __shfl_xor(a6, 32); a7 += __shfl_xor(a7, 32);

    float4 bi0 = ((const float4*)bias)[2 * q];
    float4 bi1 = ((const float4*)bias)[2 * q + 1];
    float v0 = a0 * dt + bi0.x, v1 = a1 * dt + bi0.y;
    float v2 = a2 * dt + bi0.z, v3 = a3 * dt + bi0.w;
    float v4 = a4 * dt + bi1.x, v5 = a5 * dt + bi1.y;
    float v6 = a6 * dt + bi1.z, v7 = a7 * dt + bi1.w;

    float sum = ((v0 + v1) + (v2 + v3)) + ((v4 + v5) + (v6 + v7));
    sum += __shfl_xor(sum, 1);
    sum += __shfl_xor(sum, 2);
    sum += __shfl_xor(sum, 4);
    sum += __shfl_xor(sum, 8);
    float mu = sum * (1.0f / 128.0f);
    float d0 = v0 - mu, d1 = v1 - mu, d2 = v2 - mu, d3 = v3 - mu;
    float d4 = v4 - mu, d5 = v5 - mu, d6 = v6 - mu, d7 = v7 - mu;
    float vs = ((d0 * d0 + d1 * d1) + (d2 * d2 + d3 * d3)) +
               ((d4 * d4 + d5 * d5) + (d6 * d6 + d7 * d7));
    vs += __shfl_xor(vs, 1);
    vs += __shfl_xor(vs, 2);
    vs += __shfl_xor(vs, 4);
    vs += __shfl_xor(vs, 8);
    float rstd = rsqrtf(vs * (1.0f / 128.0f) + LN_EPS);

    float4 gg0 = ((const float4*)g)[2 * q];
    float4 gg1 = ((const float4*)g)[2 * q + 1];
    float4 bb0 = ((const float4*)beta)[2 * q];
    float4 bb1 = ((const float4*)beta)[2 * q + 1];
    float o0 = fmaxf(d0 * rstd * gg0.x + bb0.x, 0.0f);
    float o1 = fmaxf(d1 * rstd * gg0.y + bb0.y, 0.0f);
    float o2 = fmaxf(d2 * rstd * gg0.z + bb0.z, 0.0f);
    float o3 = fmaxf(d3 * rstd * gg0.w + bb0.w, 0.0f);
    float o4 = fmaxf(d4 * rstd * gg1.x + bb1.x, 0.0f);
    float o5 = fmaxf(d5 * rstd * gg1.y + bb1.y, 0.0f);
    float o6 = fmaxf(d6 * rstd * gg1.z + bb1.z, 0.0f);
    float o7 = fmaxf(d7 * rstd * gg1.w + bb1.w, 0.0f);

    if (grp == 0) {  // 16 lanes cover the full row
        if (OUT_BF16) {
            uint4 pk;
            pk.x = (unsigned)f2bf(o0) | ((unsigned)f2bf(o1) << 16);
            pk.y = (unsigned)f2bf(o2) | ((unsigned)f2bf(o3) << 16);
            pk.z = (unsigned)f2bf(o4) | ((unsigned)f2bf(o5) << 16);
            pk.w = (unsigned)f2bf(o6) | ((unsigned)f2bf(o7) << 16);
            ((uint4*)out)[(size_t)wave * 16 + q] = pk;
        } else {
            float4* o = (float4*)out;
            o[(size_t)wave * 32 + 2 * q]     = make_float4(o0, o1, o2, o3);
            o[(size_t)wave * 32 + 2 * q + 1] = make_float4(o4, o5, o6, o7);
        }
    }
}

extern "C" void kernel_launch(void* const* d_in, const int* in_sizes, int n_in,
                              void* d_out, int out_size, void* d_ws, size_t ws_size,
                              hipStream_t stream) {
    const float* x   = (const float*)d_in[0];
    const int*   ei  = (const int*)d_in[1];
    const float* W1  = (const float*)d_in[2];
    const float* b1  = (const float*)d_in[3];
    const float* g1  = (const float*)d_in[4];
    const float* be1 = (const float*)d_in[5];
    const float* W2  = (const float*)d_in[6];
    const float* b2  = (const float*)d_in[7];
    const float* g2  = (const float*)d_in[8];
    const float* be2 = (const float*)d_in[9];
    float* out = (float*)d_out;

    int n  = in_sizes[0] / 128;   // 50000
    int nE = in_sizes[1] / 2;     // 800000
    const int* src = ei;
    const int* dst = ei + nE;

    int nb = (n + BSPAN - 1) >> BSH;  // 391 buckets
    int nblk64 = (n + 63) / 64;       // GEMM blocks
    int npad   = nblk64 * 64;         // padded rows for OOB-safe frag loads

    char* p = (char*)d_ws;
    auto carve = [&](size_t bytes) {
        char* r = p;
        p += (bytes + 255) & ~(size_t)255;
        return r;
    };
    float*    dinv    = (float*)carve((size_t)n * 4);
    int*      rowptr  = (int*)carve((size_t)(n + 1) * 4);
    int*      eidx    = (int*)carve((size_t)nE * 4);
    int*      gcur    = (int*)carve((size_t)nb * 4);
    unsigned* staging = (unsigned*)carve((size_t)nb * BCAP * 4);
    unsigned short* Wp1 = (unsigned short*)carve(16384 * 2);
    unsigned short* Wp2 = (unsigned short*)carve(16384 * 2);
    unsigned short* Hs  = (unsigned short*)carve((size_t)npad * 128 * 2);  // bf16 scaled GEMM out
    unsigned short* Hb  = (unsigned short*)carve((size_t)npad * 128 * 2);  // bf16 layer-1 result

    dim3 blk(256);
    int nbin = (nE + BIN_TILE - 1) / BIN_TILE;
    int nwave_blocks = (n + 3) / 4;

    // prep: W packing + gcur zero
    packw_k<<<32768 / 256, blk, 0, stream>>>(W1, W2, Wp1, Wp2, gcur, nb);

    // bucketed CSR build (bscan folded into build_k)
    bin_k<<<nbin, blk, 0, stream>>>(src, dst, gcur, staging, nE, nb);
    build_k<<<nb, blk, 0, stream>>>(staging, gcur, rowptr, eidx, dinv, n, nE);

    // layer 1 (fp32 x converted in-register inside GEMM)
    mfma_gemm_k<true><<<nblk64, blk, 0, stream>>>(x, Wp1, dinv, Hs, n);
    agg_ln_k<true><<<nwave_blocks, blk, 0, stream>>>(Hs, dinv, rowptr, eidx, b1, g1, be1, Hb, n);

    // layer 2 (Hb padding rows are garbage; OOB accum rows are discarded by store guard)
    mfma_gemm_k<false><<<nblk64, blk, 0, stream>>>(Hb, Wp2, dinv, Hs, n);
    agg_ln_k<false><<<nwave_blocks, blk, 0, stream>>>(Hs, dinv, rowptr, eidx, b2, g2, be2, out, n);
}